// Round 9
// baseline (145.594 us; speedup 1.0000x reference)
//
#include <hip/hip_runtime.h>
#include <stdint.h>

#define HW 9216
#define CDIM 128
#define WIDTH 96
#define BATCH 2

// 1/(sqrt(128)*0.1) * log2(e): folded into Q so attn epilogue is a bare exp2
#define QSCALE 1.2753324954171245f

typedef _Float16 half8 __attribute__((ext_vector_type(8)));
typedef float float4v __attribute__((ext_vector_type(4)));
typedef float float2v __attribute__((ext_vector_type(2)));

// ---------------------------------------------------------------------------
// Kernel 1: L2-normalize over C, write fp16 [B][HW][C]. Tiled: block = 64
// positions x 128 channels, values kept in registers, output staged through
// padded LDS so global stores are fully coalesced 16B/lane.
// ---------------------------------------------------------------------------
__global__ __launch_bounds__(256) void norm_kernel(const float* __restrict__ fL,
                                                   const float* __restrict__ fR,
                                                   _Float16* __restrict__ Qh,
                                                   _Float16* __restrict__ Kh)
{
    __shared__ float ssred[4][64];
    __shared__ _Float16 ot[64 * 130];   // +2 halves pad -> bank advance 1/row

    const float* src = (blockIdx.y == 0) ? fL : fR;
    _Float16* dst    = (blockIdx.y == 0) ? Qh : Kh;
    const float outScale = (blockIdx.y == 0) ? QSCALE : 1.0f;

    const int t = threadIdx.x;
    const int pos_l = t & 63, cg = t >> 6;            // 4 channel groups of 32
    const int pos0 = blockIdx.x * 64;                  // 64 | HW so no straddle
    const int b = pos0 / HW, pos_in = pos0 % HW + pos_l;

    const float* p = src + (size_t)b * CDIM * HW + pos_in;

    float v[32];
    float ss = 0.f;
    #pragma unroll
    for (int j = 0; j < 32; ++j) {
        v[j] = p[(size_t)(cg * 32 + j) * HW];
        ss += v[j] * v[j];
    }
    ssred[cg][pos_l] = ss;
    __syncthreads();
    float tot = ssred[0][pos_l] + ssred[1][pos_l] + ssred[2][pos_l] + ssred[3][pos_l];
    float scale = outScale / fmaxf(sqrtf(tot), 1e-6f);

    #pragma unroll
    for (int j = 0; j < 32; ++j)
        ot[pos_l * 130 + cg * 32 + j] = (_Float16)(v[j] * scale);
    __syncthreads();

    // coalesced write-out: 16 KB tile, 4 x uint4 per thread
    uint4* og = (uint4*)(dst + (size_t)(b * HW + pos0 % HW + 0) * CDIM);
    #pragma unroll
    for (int i = 0; i < 4; ++i) {
        int idx = i * 256 + t;            // 0..1023 dwordx4 slots
        int row = idx >> 4, chunk = idx & 15;
        og[idx] = *(const uint4*)&ot[row * 130 + chunk * 8];
    }
}

// ---------------------------------------------------------------------------
// Kernel 2: fused correlation + softmax-accumulate.
// Block: 64 q-rows x 128-key split-stream, 4 waves as 2x2 of 32q x 32k.
// BOTH Q and K live in LDS (Q staged once: 16 KB; K double-buffered 2x16 KB)
// with the XOR-chunk swizzle; all staging via global_load_lds width-16.
// Fragments re-read per kc: frees the 32-VGPR af array from the live set.
// 8 shared address VGPRs; mt/nt via +4096 imm, K buffer 1 via +16384 imm.
// amdgpu_waves_per_eu(2,4): allocator budget 128 VGPR (rounds 4/7: default
// heuristic shrinks to 64 arch VGPRs + accvgpr ping-pong = 3x epilogue VALU).
// No online max needed: |logit2| <= 1.28.
// ---------------------------------------------------------------------------
__global__ __launch_bounds__(256)
__attribute__((amdgpu_waves_per_eu(2, 4)))
void attn_kernel(const _Float16* __restrict__ Qh,
                 const _Float16* __restrict__ Kh,
                 float4* __restrict__ part)
{
    // [0,16384): K buf0 | [16384,32768): K buf1 | [32768,49152): Q tile
    __shared__ _Float16 lds[3 * 64 * 128];

    const int qt = blockIdx.x, split = blockIdx.y, b = blockIdx.z;
    const int t = threadIdx.x;
    const int lane = t & 63, wave = t >> 6;
    const int wq = wave >> 1, wk = wave & 1;       // 2x2 waves over 64q x 64k
    const int lane15 = lane & 15, quad = lane >> 4;

    const int kbase0 = split * 1152;
    const char* kp0 = (const char*)(Kh + (size_t)b * HW * CDIM) + (size_t)kbase0 * 256;
    const char* qp0 = (const char*)(Qh + (size_t)(b * HW + qt * 64) * CDIM);

    // fixed per-lane staging voffsets: wave w covers rows [w*16, w*16+16)
    // LDS dest linear (instr adds lane*16B); source chunk XOR-swizzled so
    // LDS[r][c] = SRC[r][c ^ (r&15)] -> conflict-free fragment reads.
    int voff[4];
    #pragma unroll
    for (int i = 0; i < 4; ++i) {
        int r = wave * 16 + i * 4 + quad;
        voff[i] = r * 256 + ((lane15 ^ (r & 15)) << 4);
    }

    #define STAGE(SRCP, LDSOFF)                                                  \
        {                                                                        \
            _Float16* db_ = &lds[(LDSOFF) / 2 + wave * 16 * 128];                \
            _Pragma("unroll")                                                    \
            for (int i_ = 0; i_ < 4; ++i_)                                       \
                __builtin_amdgcn_global_load_lds(                                \
                    (const __attribute__((address_space(1))) uint32_t*)((SRCP) + voff[i_]), \
                    (__attribute__((address_space(3))) uint32_t*)(db_ + i_ * 4 * 128),      \
                    16, 0, 0);                                                   \
        }

    // ---- shared per-kc fragment addresses (8 VGPR):
    // K frag (nt=0):  ((wk*32+lane15)<<8) + chunk(kc);  nt=1 -> +4096 imm
    // Q frag (mt=0):  32768 + ((wq*32+lane15)<<8) + chunk(kc); mt=1 -> +4096
    // K buffer 1 -> +16384 imm.  chunk(kc) = ((kc*4+quad)^lane15)<<4
    int kaddr[4], qaddr[4];
    #pragma unroll
    for (int kc = 0; kc < 4; ++kc) {
        int chunk = (((kc * 4 + quad) ^ lane15) << 4);
        kaddr[kc] = ((wk * 32 + lane15) << 8) + chunk;
        qaddr[kc] = 32768 + ((wq * 32 + lane15) << 8) + chunk;
    }
    const char* ldsb = (const char*)&lds[0];

    // ---- 3-phase coordinate tables (kbase0 % 96 == 0, period-3 in kt) ----
    float xph[3][2], yph[3][2];
    {
        int off0 = wk * 32 + lane15;
        #pragma unroll
        for (int p = 0; p < 3; ++p) {
            #pragma unroll
            for (int nt = 0; nt < 2; ++nt) {
                int k = p * 64 + off0 + nt * 16;
                xph[p][nt] = (float)(k % 96);
                yph[p][nt] = (float)(split * 12 + k / 96);
            }
        }
    }

    float2v l2[4], ax2[4], ay2[4], mx2[4];   // p = mt*2 + rpair (q-rows)
    #pragma unroll
    for (int p = 0; p < 4; ++p) {
        l2[p] = (float2v)0.f; ax2[p] = (float2v)0.f; ay2[p] = (float2v)0.f;
        mx2[p] = (float2v)(-1.0e30f);
    }

    STAGE(qp0, 32768);     // Q tile, once
    STAGE(kp0, 0);         // K tile 0 -> buf0
    __syncthreads();

    #pragma unroll
    for (int kt = 0; kt < 18; ++kt) {
        const int cur = kt & 1;              // compile-time
        const int phase = kt % 3;            // compile-time
        const float yadd = (float)(2 * (kt / 3));   // compile-time literal

        float4v acc[2][2];
        #pragma unroll
        for (int kc = 0; kc < 4; ++kc) {
            half8 af[2], bf[2];
            #pragma unroll
            for (int mt = 0; mt < 2; ++mt)
                af[mt] = *(const half8*)(ldsb + qaddr[kc] + mt * 4096);
            #pragma unroll
            for (int nt = 0; nt < 2; ++nt)
                bf[nt] = *(const half8*)(ldsb + cur * 16384 + kaddr[kc] + nt * 4096);
            #pragma unroll
            for (int mt = 0; mt < 2; ++mt)
                #pragma unroll
                for (int nt = 0; nt < 2; ++nt)
                    acc[mt][nt] = __builtin_amdgcn_mfma_f32_16x16x32_f16(
                        af[mt], bf[nt],
                        (kc == 0) ? (float4v)0.f : acc[mt][nt], 0, 0, 0);
        }

        // async prefetch of the next tile overlaps the VALU epilogue below
        if (kt < 17) STAGE(kp0 + (kt + 1) * 16384, (1 - cur) * 16384);

        // ---- fused softmax-accumulate epilogue (packed fp32 pairs) ----
        #pragma unroll
        for (int nt = 0; nt < 2; ++nt) {
            float2v xf2 = (float2v)(xph[phase][nt]);
            float2v yf2 = (float2v)(yph[phase][nt] + yadd);
            #pragma unroll
            for (int mt = 0; mt < 2; ++mt) {
                #pragma unroll
                for (int rp = 0; rp < 2; ++rp) {              // C/D row = quad*4+r
                    float2v lg;
                    lg.x = acc[mt][nt][2 * rp];
                    lg.y = acc[mt][nt][2 * rp + 1];
                    float2v e;
                    e.x = __builtin_exp2f(lg.x);
                    e.y = __builtin_exp2f(lg.y);
                    int p = mt * 2 + rp;
                    l2[p]  += e;
                    ax2[p] += e * xf2;
                    ay2[p] += e * yf2;
                    mx2[p] = __builtin_elementwise_max(mx2[p], lg);
                }
            }
        }
        __syncthreads();   // readers of cur done + prefetch drained
    }

    // reduce over the 16 columns (lanes sharing a quad)
    #pragma unroll
    for (int p = 0; p < 4; ++p) {
        #pragma unroll
        for (int m = 1; m < 16; m <<= 1) {
            l2[p].x  += __shfl_xor(l2[p].x,  m, 64);
            l2[p].y  += __shfl_xor(l2[p].y,  m, 64);
            ax2[p].x += __shfl_xor(ax2[p].x, m, 64);
            ax2[p].y += __shfl_xor(ax2[p].y, m, 64);
            ay2[p].x += __shfl_xor(ay2[p].x, m, 64);
            ay2[p].y += __shfl_xor(ay2[p].y, m, 64);
            mx2[p].x  = fmaxf(mx2[p].x, __shfl_xor(mx2[p].x, m, 64));
            mx2[p].y  = fmaxf(mx2[p].y, __shfl_xor(mx2[p].y, m, 64));
        }
    }

    // part layout: [s=split*2+wk][b*HW + row] -> coalesced stores & loads
    if (lane15 == 0) {
        #pragma unroll
        for (int p = 0; p < 4; ++p) {
            int mt = p >> 1, rp = p & 1;
            #pragma unroll
            for (int comp = 0; comp < 2; ++comp) {
                int r = 2 * rp + comp;
                int row = qt * 64 + wq * 32 + mt * 16 + quad * 4 + r;
                float lv  = comp ? l2[p].y  : l2[p].x;
                float axv = comp ? ax2[p].y : ax2[p].x;
                float ayv = comp ? ay2[p].y : ay2[p].x;
                float mxv = __builtin_exp2f(comp ? mx2[p].y : mx2[p].x);
                part[(size_t)(split * 2 + wk) * (BATCH * HW) + b * HW + row] =
                    make_float4(lv, axv, ayv, mxv);
            }
        }
    }
    #undef STAGE
}

// ---------------------------------------------------------------------------
// Kernel 3: combine 16 partials per query row, write flow + conf
// ---------------------------------------------------------------------------
__global__ __launch_bounds__(256) void combine_kernel(const float4* __restrict__ part,
                                                      float* __restrict__ out)
{
    int tid = blockIdx.x * 256 + threadIdx.x;   // 0 .. B*HW-1 (grid sized exactly)
    int b = tid / HW, pos = tid % HW;
    float l = 0.f, ax = 0.f, ay = 0.f, mx = 0.f;
    #pragma unroll
    for (int s = 0; s < 16; ++s) {
        float4 v = part[(size_t)s * (BATCH * HW) + tid];   // coalesced
        l += v.x; ax += v.y; ay += v.z; mx = fmaxf(mx, v.w);
    }
    float inv = 1.0f / l;
    int x = pos % WIDTH, y = pos / WIDTH;
    out[(size_t)b * 2 * HW + pos]           = ax * inv - (float)x;
    out[(size_t)b * 2 * HW + HW + pos]      = ay * inv - (float)y;
    out[(size_t)BATCH * 2 * HW + (size_t)b * HW + pos] = mx * inv;
}

// ---------------------------------------------------------------------------
extern "C" void kernel_launch(void* const* d_in, const int* in_sizes, int n_in,
                              void* d_out, int out_size, void* d_ws, size_t ws_size,
                              hipStream_t stream)
{
    const float* fL = (const float*)d_in[0];
    const float* fR = (const float*)d_in[1];
    float* out = (float*)d_out;

    char* ws = (char*)d_ws;
    const size_t QH_BYTES = (size_t)BATCH * HW * CDIM * sizeof(_Float16);  // 4.72 MB
    _Float16* Qh  = (_Float16*)ws;
    _Float16* Kh  = (_Float16*)(ws + QH_BYTES);
    float4*   part = (float4*)(ws + 2 * QH_BYTES);                         // 4.72 MB

    norm_kernel<<<dim3((BATCH * HW) / 64, 2), 256, 0, stream>>>(fL, fR, Qh, Kh);
    attn_kernel<<<dim3(HW / 64, 8, BATCH), 256, 0, stream>>>(Qh, Kh, part);
    combine_kernel<<<dim3((BATCH * HW) / 256), 256, 0, stream>>>(part, out);
}

// Round 10
// 134.765 us; speedup vs baseline: 1.0803x; 1.0803x over previous
//
#include <hip/hip_runtime.h>
#include <stdint.h>

#define HW 9216
#define CDIM 128
#define WIDTH 96
#define BATCH 2

// 1/(sqrt(128)*0.1) * log2(e): folded into Q so attn epilogue is a bare exp2
#define QSCALE 1.2753324954171245f

typedef _Float16 half8 __attribute__((ext_vector_type(8)));
typedef float float4v __attribute__((ext_vector_type(4)));
typedef float float2v __attribute__((ext_vector_type(2)));

// ---------------------------------------------------------------------------
// Kernel 1: L2-normalize over C, write fp16 [B][HW][C]. Tiled: block = 64
// positions x 128 channels, values kept in registers, output staged through
// padded LDS so global stores are fully coalesced 16B/lane.
// ---------------------------------------------------------------------------
__global__ __launch_bounds__(256) void norm_kernel(const float* __restrict__ fL,
                                                   const float* __restrict__ fR,
                                                   _Float16* __restrict__ Qh,
                                                   _Float16* __restrict__ Kh)
{
    __shared__ float ssred[4][64];
    __shared__ _Float16 ot[64 * 130];   // +2 halves pad -> bank advance 1/row

    const float* src = (blockIdx.y == 0) ? fL : fR;
    _Float16* dst    = (blockIdx.y == 0) ? Qh : Kh;
    const float outScale = (blockIdx.y == 0) ? QSCALE : 1.0f;

    const int t = threadIdx.x;
    const int pos_l = t & 63, cg = t >> 6;            // 4 channel groups of 32
    const int pos0 = blockIdx.x * 64;                  // 64 | HW so no straddle
    const int b = pos0 / HW, pos_in = pos0 % HW + pos_l;

    const float* p = src + (size_t)b * CDIM * HW + pos_in;

    float v[32];
    float ss = 0.f;
    #pragma unroll
    for (int j = 0; j < 32; ++j) {
        v[j] = p[(size_t)(cg * 32 + j) * HW];
        ss += v[j] * v[j];
    }
    ssred[cg][pos_l] = ss;
    __syncthreads();
    float tot = ssred[0][pos_l] + ssred[1][pos_l] + ssred[2][pos_l] + ssred[3][pos_l];
    float scale = outScale / fmaxf(sqrtf(tot), 1e-6f);

    #pragma unroll
    for (int j = 0; j < 32; ++j)
        ot[pos_l * 130 + cg * 32 + j] = (_Float16)(v[j] * scale);
    __syncthreads();

    // coalesced write-out: 16 KB tile, 4 x uint4 per thread
    uint4* og = (uint4*)(dst + (size_t)(b * HW + pos0 % HW + 0) * CDIM);
    #pragma unroll
    for (int i = 0; i < 4; ++i) {
        int idx = i * 256 + t;            // 0..1023 dwordx4 slots
        int row = idx >> 4, chunk = idx & 15;
        og[idx] = *(const uint4*)&ot[row * 130 + chunk * 8];
    }
}

// ---------------------------------------------------------------------------
// Kernel 2: fused correlation + softmax-accumulate.
// Block: 64 q-rows x 128-key split-stream, 4 waves as 2x2 of 32q x 32k.
// Q fragments in registers, K double-buffered 2x16 KB LDS (XOR-chunk
// swizzle, global_load_lds width-16), ONE barrier per 64-key tile.
// Prefetch issued BEFORE the MFMA loop: ds-wait + 16 MFMA + epilogue
// (~400+ cyc) cover the load latency before the barrier's vmcnt drain.
// exp2 via __builtin_amdgcn_exp2f = bare v_exp_f32 (default exp2f lowering
// carries denormal-range fixup VALU; |logit2| <= 1.28 so unneeded).
// No online max needed.
// ---------------------------------------------------------------------------
__global__ __launch_bounds__(256) void attn_kernel(const _Float16* __restrict__ Qh,
                                                   const _Float16* __restrict__ Kh,
                                                   float4* __restrict__ part)
{
    __shared__ _Float16 Ks[2 * 64 * 128];   // 2 x 16 KB double buffer

    const int qt = blockIdx.x, split = blockIdx.y, b = blockIdx.z;
    const int t = threadIdx.x;
    const int lane = t & 63, wave = t >> 6;
    const int wq = wave >> 1, wk = wave & 1;       // 2x2 waves over 64q x 64k
    const int lane15 = lane & 15, quad = lane >> 4;

    // ---- Q fragments direct from global (once per block): 8 x half8 = 32 VGPR
    half8 af[2][4];   // [mt][kc]
    {
        const char* qb = (const char*)(Qh +
            ((size_t)(b * HW + qt * 64 + wq * 32 + lane15)) * CDIM);
        #pragma unroll
        for (int mt = 0; mt < 2; ++mt)
            #pragma unroll
            for (int kc = 0; kc < 4; ++kc)
                af[mt][kc] = *(const half8*)(qb + mt * 16 * 256 + kc * 64 + quad * 16);
    }

    const int kbase0 = split * 1152;
    const char* kp0 = (const char*)(Kh + (size_t)b * HW * CDIM) + (size_t)kbase0 * 256;

    // fixed per-lane staging voffsets: wave handles rows [wave*16, wave*16+16)
    // LDS dest linear (instr adds lane*16B); source chunk XOR-swizzled so
    // LDS[r][c'] = K[r][c' ^ (r&15)] -> conflict-free fragment reads.
    int voff[4];
    #pragma unroll
    for (int i = 0; i < 4; ++i) {
        int r = wave * 16 + i * 4 + quad;
        voff[i] = r * 256 + ((lane15 ^ (r & 15)) << 4);
    }

    #define STAGE(TILE, BUF)                                                     \
        {                                                                        \
            const char* kb_ = kp0 + (TILE) * 16384;                              \
            _Float16* db_ = &Ks[(BUF) * 8192 + wave * 16 * 128];                 \
            _Pragma("unroll")                                                    \
            for (int i_ = 0; i_ < 4; ++i_)                                       \
                __builtin_amdgcn_global_load_lds(                                \
                    (const __attribute__((address_space(1))) uint32_t*)(kb_ + voff[i_]), \
                    (__attribute__((address_space(3))) uint32_t*)(db_ + i_ * 4 * 128),   \
                    16, 0, 0);                                                   \
        }

    // ---- precomputed LDS fragment read addresses (loop-invariant, 8 VGPR) ----
    // byte addr of buffer-0 fragment; buffer 1 = same + 16384 (imm offset)
    int rdoff[2][4];
    #pragma unroll
    for (int nt = 0; nt < 2; ++nt)
        #pragma unroll
        for (int kc = 0; kc < 4; ++kc)
            rdoff[nt][kc] = ((wk * 32 + nt * 16 + lane15) << 8) +
                            (((kc * 4 + quad) ^ lane15) << 4);
    const char* ksb = (const char*)&Ks[0];

    // ---- 3-phase coordinate tables (kbase0 % 96 == 0, period-3 in kt) ----
    float xph[3][2], yph[3][2];
    {
        int off0 = wk * 32 + lane15;
        #pragma unroll
        for (int p = 0; p < 3; ++p) {
            #pragma unroll
            for (int nt = 0; nt < 2; ++nt) {
                int k = p * 64 + off0 + nt * 16;
                xph[p][nt] = (float)(k % 96);
                yph[p][nt] = (float)(split * 12 + k / 96);
            }
        }
    }

    float2v l2[4], ax2[4], ay2[4], mx2[4];   // p = mt*2 + rpair (q-rows)
    #pragma unroll
    for (int p = 0; p < 4; ++p) {
        l2[p] = (float2v)0.f; ax2[p] = (float2v)0.f; ay2[p] = (float2v)0.f;
        mx2[p] = (float2v)(-1.0e30f);
    }

    STAGE(0, 0);
    __syncthreads();

    #pragma unroll
    for (int kt = 0; kt < 18; ++kt) {
        const int cur = kt & 1;              // compile-time
        const int phase = kt % 3;            // compile-time
        const float yadd = (float)(2 * (kt / 3));   // compile-time literal

        // prefetch next tile FIRST: covered by ds-wait + MFMA + epilogue
        if (kt < 17) STAGE(kt + 1, 1 - cur);

        float4v acc[2][2];
        #pragma unroll
        for (int kc = 0; kc < 4; ++kc) {
            half8 bf[2];
            #pragma unroll
            for (int nt = 0; nt < 2; ++nt)
                bf[nt] = *(const half8*)(ksb + cur * 16384 + rdoff[nt][kc]);
            #pragma unroll
            for (int mt = 0; mt < 2; ++mt)
                #pragma unroll
                for (int nt = 0; nt < 2; ++nt)
                    acc[mt][nt] = __builtin_amdgcn_mfma_f32_16x16x32_f16(
                        af[mt][kc], bf[nt],
                        (kc == 0) ? (float4v)0.f : acc[mt][nt], 0, 0, 0);
        }

        // ---- fused softmax-accumulate epilogue (bare v_exp_f32 + packed) ----
        #pragma unroll
        for (int nt = 0; nt < 2; ++nt) {
            float2v xf2 = (float2v)(xph[phase][nt]);
            float2v yf2 = (float2v)(yph[phase][nt] + yadd);
            #pragma unroll
            for (int mt = 0; mt < 2; ++mt) {
                #pragma unroll
                for (int rp = 0; rp < 2; ++rp) {              // C/D row = quad*4+r
                    float2v lg;
                    lg.x = acc[mt][nt][2 * rp];
                    lg.y = acc[mt][nt][2 * rp + 1];
                    float2v e;
                    e.x = __builtin_amdgcn_exp2f(lg.x);
                    e.y = __builtin_amdgcn_exp2f(lg.y);
                    int p = mt * 2 + rp;
                    l2[p]  += e;
                    ax2[p] += e * xf2;
                    ay2[p] += e * yf2;
                    mx2[p] = __builtin_elementwise_max(mx2[p], lg);
                }
            }
        }
        __syncthreads();   // readers of cur done + prefetch drained
    }

    // reduce over the 16 columns (lanes sharing a quad)
    #pragma unroll
    for (int p = 0; p < 4; ++p) {
        #pragma unroll
        for (int m = 1; m < 16; m <<= 1) {
            l2[p].x  += __shfl_xor(l2[p].x,  m, 64);
            l2[p].y  += __shfl_xor(l2[p].y,  m, 64);
            ax2[p].x += __shfl_xor(ax2[p].x, m, 64);
            ax2[p].y += __shfl_xor(ax2[p].y, m, 64);
            ay2[p].x += __shfl_xor(ay2[p].x, m, 64);
            ay2[p].y += __shfl_xor(ay2[p].y, m, 64);
            mx2[p].x  = fmaxf(mx2[p].x, __shfl_xor(mx2[p].x, m, 64));
            mx2[p].y  = fmaxf(mx2[p].y, __shfl_xor(mx2[p].y, m, 64));
        }
    }

    // part layout: [s=split*2+wk][b*HW + row] -> coalesced stores & loads
    if (lane15 == 0) {
        #pragma unroll
        for (int p = 0; p < 4; ++p) {
            int mt = p >> 1, rp = p & 1;
            #pragma unroll
            for (int comp = 0; comp < 2; ++comp) {
                int r = 2 * rp + comp;
                int row = qt * 64 + wq * 32 + mt * 16 + quad * 4 + r;
                float lv  = comp ? l2[p].y  : l2[p].x;
                float axv = comp ? ax2[p].y : ax2[p].x;
                float ayv = comp ? ay2[p].y : ay2[p].x;
                float mxv = __builtin_amdgcn_exp2f(comp ? mx2[p].y : mx2[p].x);
                part[(size_t)(split * 2 + wk) * (BATCH * HW) + b * HW + row] =
                    make_float4(lv, axv, ayv, mxv);
            }
        }
    }
    #undef STAGE
}

// ---------------------------------------------------------------------------
// Kernel 3: combine 16 partials per query row, write flow + conf
// ---------------------------------------------------------------------------
__global__ __launch_bounds__(256) void combine_kernel(const float4* __restrict__ part,
                                                      float* __restrict__ out)
{
    int tid = blockIdx.x * 256 + threadIdx.x;   // 0 .. B*HW-1 (grid sized exactly)
    int b = tid / HW, pos = tid % HW;
    float l = 0.f, ax = 0.f, ay = 0.f, mx = 0.f;
    #pragma unroll
    for (int s = 0; s < 16; ++s) {
        float4 v = part[(size_t)s * (BATCH * HW) + tid];   // coalesced
        l += v.x; ax += v.y; ay += v.z; mx = fmaxf(mx, v.w);
    }
    float inv = 1.0f / l;
    int x = pos % WIDTH, y = pos / WIDTH;
    out[(size_t)b * 2 * HW + pos]           = ax * inv - (float)x;
    out[(size_t)b * 2 * HW + HW + pos]      = ay * inv - (float)y;
    out[(size_t)BATCH * 2 * HW + (size_t)b * HW + pos] = mx * inv;
}

// ---------------------------------------------------------------------------
extern "C" void kernel_launch(void* const* d_in, const int* in_sizes, int n_in,
                              void* d_out, int out_size, void* d_ws, size_t ws_size,
                              hipStream_t stream)
{
    const float* fL = (const float*)d_in[0];
    const float* fR = (const float*)d_in[1];
    float* out = (float*)d_out;

    char* ws = (char*)d_ws;
    const size_t QH_BYTES = (size_t)BATCH * HW * CDIM * sizeof(_Float16);  // 4.72 MB
    _Float16* Qh  = (_Float16*)ws;
    _Float16* Kh  = (_Float16*)(ws + QH_BYTES);
    float4*   part = (float4*)(ws + 2 * QH_BYTES);                         // 4.72 MB

    norm_kernel<<<dim3((BATCH * HW) / 64, 2), 256, 0, stream>>>(fL, fR, Qh, Kh);
    attn_kernel<<<dim3(HW / 64, 8, BATCH), 256, 0, stream>>>(Qh, Kh, part);
    combine_kernel<<<dim3((BATCH * HW) / 256), 256, 0, stream>>>(part, out);
}